// Round 12
// baseline (243.667 us; speedup 1.0000x reference)
//
#include <hip/hip_runtime.h>
#include <hip/hip_bf16.h>
#include <cstdint>
#include <cstddef>

#define BQ 128        // queries (problem-fixed)
#define DK 192        // SIG_DIM
#define KTOP 32
#define CHI 32        // gallery items per chunk
#define SLOTS 2       // candidate slots per (query, chunk)
#define QCAP 512      // per-chunk LDS rescore queue
#define OCAP 65536    // global overflow list
#define MARGIN 0.02f  // > 2x (trunc-G + rne-Q) dot error bound (~0.012)
#define THRV 3200     // thr32 LDS value slots
#define GRIDP 768     // persistent blocks (3/CU); also sample count
#define CNTL 6400     // select: LDS-cached per-chunk counts

#define NEG_INF (-__builtin_huge_valf())

typedef short short8v __attribute__((ext_vector_type(8)));
typedef float f32x16  __attribute__((ext_vector_type(16)));

__device__ __forceinline__ unsigned fkey(float s) {
    unsigned u = __float_as_uint(s);
    return (u & 0x80000000u) ? ~u : (u | 0x80000000u);   // monotone f32 -> u32
}
__device__ __forceinline__ bool pri_gt(float s1, int i1, float s2, int i2) {
    return (s1 > s2) || (s1 == s2 && i1 < i2);           // jax top_k stability
}
// pack {bf16_trunc(b) : bf16_trunc(a)} in one v_perm_b32 (high halves)
__device__ __forceinline__ unsigned pk_trunc(float a, float b) {
    return __builtin_amdgcn_perm(__float_as_uint(b), __float_as_uint(a),
                                 0x07060302u);
}
__device__ __forceinline__ unsigned f2bf_rne(float x) {
    unsigned u = __float_as_uint(x);
    unsigned r = u + 0x7FFFu + ((u >> 16) & 1u);
    return r >> 16;
}
__device__ __forceinline__ float dot192(const float* __restrict__ a,
                                        const float* __restrict__ b) {
    float s = 0.f;
    #pragma unroll 8
    for (int k = 0; k < DK; ++k) s = fmaf(a[k], b[k], s);
    return s;
}
// async global->LDS DMA, 16B per lane; lptr is wave-uniform base (HW adds lane*16)
__device__ __forceinline__ void gload_lds16(const void* g, void* l) {
    __builtin_amdgcn_global_load_lds(
        (const __attribute__((address_space(1))) unsigned int*)g,
        (__attribute__((address_space(3))) unsigned int*)l,
        16, 0, 0);
}

// ---------------------------------------------------------------------------
// MFMA scoring pass over 32-item chunks x all 128 queries.
// G staged fp32 via global_load_lds (async DMA, ZERO staging VGPRs); source
// addresses pre-XOR-swizzled so LDS reads are ~conflict-free; fp32->bf16 at
// fragment-read time (v_perm). Q fragments hoisted to 48 VGPRs per block.
// MODE 0: sampled chunks (1/block): masked per-(chunk,q) bf16 max -> gmax
// MODE 1: persistent filter: one-ahead DMA pipeline, threshold filter ->
//         LDS queue -> exact fp32 rescore -> slotted store
// amdgpu_waves_per_eu(3,4): VGPR budget 128..168, live ~100 => NO SPILLS.
// ---------------------------------------------------------------------------
template<int MODE>
__global__ __attribute__((amdgpu_waves_per_eu(3, 4))) __launch_bounds__(256)
void score_pass(
    const float* __restrict__ Qf, const float* __restrict__ G,
    const int* __restrict__ mask, const float* __restrict__ thrm,
    float* __restrict__ gmax,
    int* __restrict__ cnt2, float* __restrict__ cs, int* __restrict__ ci,
    int* __restrict__ ocnt, int* __restrict__ oq, int* __restrict__ og,
    float* __restrict__ osv,
    int Ntot, int NCH, int SC)
{
    __shared__ float    Gf[2][CHI * DK];   // fp32 staged tiles (2 x 24 KB)
    __shared__ float    thrmS[BQ];
    __shared__ unsigned queue[QCAP];
    __shared__ int      lcnt[BQ];
    __shared__ int      qn;

    const int t = threadIdx.x;
    const int w = t >> 6, lane = t & 63;
    const int lo5 = lane & 31, hi = lane >> 5;
    const int qbW = w * 32;

    if (t < BQ) { thrmS[t] = (MODE == 1) ? thrm[t] : 0.f; lcnt[t] = 0; }
    if (t == 0) qn = 0;

    // hoist Q fragments once per block (RNE fp32->bf16 in-register)
    uint4 aF[12];
    {
        const float* qp = Qf + (size_t)(qbW + lo5) * DK + hi * 8;
        #pragma unroll
        for (int s = 0; s < 12; ++s) {
            float4 x = *reinterpret_cast<const float4*>(qp + s * 16);
            float4 y = *reinterpret_cast<const float4*>(qp + s * 16 + 4);
            aF[s].x = f2bf_rne(x.x) | (f2bf_rne(x.y) << 16);
            aF[s].y = f2bf_rne(x.z) | (f2bf_rne(x.w) << 16);
            aF[s].z = f2bf_rne(y.x) | (f2bf_rne(y.y) << 16);
            aF[s].w = f2bf_rne(y.z) | (f2bf_rne(y.w) << 16);
        }
    }

    // per-lane staging geometry: slot = i*256+t covers 32 rows x 48 16B-blocks
    int srow[6], swz[6];
    #pragma unroll
    for (int i = 0; i < 6; ++i) {
        const int slot = t + i * 256;
        const int r = slot / 48, c = slot - r * 48;
        srow[i] = r;
        swz[i]  = ((c ^ (r & 7)) << 4);    // pre-swizzled global 16B block
    }

    auto STAGE = [&](int chunk, int buf) {
        const size_t cb = (size_t)chunk * CHI;
        #pragma unroll
        for (int i = 0; i < 6; ++i) {
            size_t grow = cb + srow[i];
            if (grow >= (size_t)Ntot) grow = (size_t)Ntot - 1;  // safe dup
            const char* gp = (const char*)G + grow * (DK * 4) + swz[i];
            char* lp = (char*)&Gf[buf][0] + ((i << 2) + w) * 1024; // wave-uniform
            gload_lds16(gp, lp);
        }
    };

    const int step = (MODE == 0) ? 1 : (int)gridDim.x;
    int c = blockIdx.x;
    const int cEnd = (MODE == 0) ? (blockIdx.x + 1) : NCH;
    auto CHUNK_OF = [&](int idx) {
        return (MODE == 0) ? (int)(((long long)idx * NCH) / SC) : idx;
    };

    if (c < cEnd) STAGE(CHUNK_OF(c), 0);
    __syncthreads();                       // drains DMA (vmcnt) + init
    int pb = 0;

    const char* const rowp0 = (const char*)&Gf[0][0];
    const unsigned rowoff = (unsigned)(lo5 * (DK * 4));
    const unsigned xsh = (unsigned)((lo5 & 7) << 4);

    while (c < cEnd) {
        const int ch = CHUNK_OF(c);
        const int cb = ch * CHI;
        const int cn = c + step;
        const bool more = cn < cEnd;
        if (more) STAGE(CHUNK_OF(cn), pb ^ 1);   // async under this compute

        const char* rowp = rowp0 + (size_t)pb * (CHI * DK * 4) + rowoff;
        f32x16 acc = {0,0,0,0,0,0,0,0,0,0,0,0,0,0,0,0};
        #pragma unroll
        for (int s = 0; s < 12; ++s) {
            const unsigned b0 = ((unsigned)((s * 4 + hi * 2) << 4)) ^ xsh;
            const unsigned b1 = ((unsigned)((s * 4 + hi * 2 + 1) << 4)) ^ xsh;
            float4 f0 = *reinterpret_cast<const float4*>(rowp + b0);
            float4 f1 = *reinterpret_cast<const float4*>(rowp + b1);
            union { unsigned u[4]; short8v v; } bu;
            bu.u[0] = pk_trunc(f0.x, f0.y); bu.u[1] = pk_trunc(f0.z, f0.w);
            bu.u[2] = pk_trunc(f1.x, f1.y); bu.u[3] = pk_trunc(f1.z, f1.w);
            union { uint4 u; short8v v; } au; au.u = aF[s];
            acc = __builtin_amdgcn_mfma_f32_32x32x16_bf16(au.v, bu.v, acc, 0, 0, 0);
        }

        // C layout (32x32): col(item)=lane&31, row(query)=(j&3)+8*(j>>2)+4*hi
        if (MODE == 0) {
            #pragma unroll
            for (int j = 0; j < 16; ++j) {
                const int row = (j & 3) + 8 * (j >> 2) + 4 * hi;
                const int q = qbW + row;
                const int g = cb + lo5;
                float m = NEG_INF;
                if (g < Ntot && !mask[(size_t)q * (size_t)Ntot + g])
                    m = acc[j];
                #pragma unroll
                for (int off = 1; off < 32; off <<= 1)
                    m = fmaxf(m, __shfl_xor(m, off));
                if (lo5 == 0) gmax[(size_t)c * BQ + q] = m;   // sample index
            }
        } else {
            #pragma unroll
            for (int j = 0; j < 16; ++j) {
                const int row = (j & 3) + 8 * (j >> 2) + 4 * hi;
                const int q = qbW + row;
                const float th = thrmS[q];
                const int g = cb + lo5;
                const float s = acc[j];
                if (g < Ntot && s >= th) {
                    if (!mask[(size_t)q * (size_t)Ntot + g]) {
                        const int p = atomicAdd(&qn, 1);
                        if (p < QCAP) {
                            queue[p] = ((unsigned)q << 24) | (unsigned)g;
                        } else {   // pathological: inline exact rescore
                            float sx = dot192(Qf + q * DK, G + (size_t)g * DK);
                            const int op = atomicAdd(ocnt, 1);
                            if (op < OCAP) { oq[op] = q; og[op] = g; osv[op] = sx; }
                        }
                    }
                }
            }
            __syncthreads();
            const int nq = qn < QCAP ? qn : QCAP;
            for (int cc = w; cc < nq; cc += 4) {       // one wave per candidate
                const unsigned pk = queue[cc];
                const int q = pk >> 24, g = pk & 0xFFFFFF;
                const float* qr = Qf + q * DK;
                const float* gr = G + (size_t)g * DK;
                const int k0 = lane * 3;
                float part = qr[k0] * gr[k0];
                part = fmaf(qr[k0 + 1], gr[k0 + 1], part);
                part = fmaf(qr[k0 + 2], gr[k0 + 2], part);
                #pragma unroll
                for (int off = 32; off > 0; off >>= 1)
                    part += __shfl_xor(part, off);
                if (lane == 0) {
                    const int p = atomicAdd(&lcnt[q], 1);
                    if (p < SLOTS) {
                        const size_t o = ((size_t)q * NCH + ch) * SLOTS + p;
                        cs[o] = part; ci[o] = g;
                    } else {
                        const int op = atomicAdd(ocnt, 1);
                        if (op < OCAP) { oq[op] = q; og[op] = g; osv[op] = part; }
                    }
                }
            }
            __syncthreads();
            if (t < BQ) {
                int v = lcnt[t]; if (v > SLOTS) v = SLOTS;
                cnt2[(size_t)t * NCH + ch] = v;
                lcnt[t] = 0;
            }
            if (t == 0) qn = 0;
        }

        __syncthreads();   // next tile's DMA drained; LDS reuse safe
        pb ^= 1;
        c = cn;
    }
}

// ---------------------------------------------------------------------------
// thrm[q] = (exact 32nd-largest of SC sampled masked chunk-maxima) - MARGIN.
// Valid bound: 32 distinct unmasked witnesses with bf16 score >= thr.
// ---------------------------------------------------------------------------
__global__ __launch_bounds__(256) void thr32(
    const float* __restrict__ gmax, float* __restrict__ thrm, int SC)
{
    __shared__ float vals[THRV];
    __shared__ int hist[256];
    __shared__ int hscan[256];
    __shared__ int bS, gtS;

    const int q = blockIdx.x;
    const int t = threadIdx.x;
    const int M = SC < THRV ? SC : THRV;

    for (int i = t; i < M; i += 256) {
        float m = gmax[(size_t)i * BQ + q];
        for (int j = i + THRV; j < SC; j += THRV)
            m = fmaxf(m, gmax[(size_t)j * BQ + q]);
        vals[i] = m;
    }
    __syncthreads();

    unsigned prefix = 0, pmask = 0;
    int kneed = KTOP;
    for (int pass = 0; pass < 4; ++pass) {
        const int shift = 24 - pass * 8;
        hist[t] = 0;
        __syncthreads();
        for (int i = t; i < M; i += 256) {
            unsigned k = fkey(vals[i]);
            if ((k & pmask) == prefix) atomicAdd(&hist[(k >> shift) & 255], 1);
        }
        __syncthreads();
        int* src = hist; int* dst = hscan;
        for (int off = 1; off < 256; off <<= 1) {
            int v = src[t] + ((t + off) < 256 ? src[t + off] : 0);
            __syncthreads();
            dst[t] = v;
            __syncthreads();
            int* tmp = src; src = dst; dst = tmp;
        }
        if (src[t] >= kneed && (t == 255 || src[t + 1] < kneed)) {
            bS = t; gtS = (t == 255) ? 0 : src[t + 1];
        }
        __syncthreads();
        kneed -= gtS;
        prefix |= ((unsigned)bS) << shift;
        pmask  |= 0xFFu << shift;
        __syncthreads();
    }
    if (t == 0) {
        unsigned u = (prefix & 0x80000000u) ? (prefix & 0x7FFFFFFFu) : ~prefix;
        thrm[q] = __uint_as_float(u) - MARGIN;
    }
}

// ---------------------------------------------------------------------------
// Exact per-query top-32 over slotted candidates (+overflow): 4-pass radix
// select + collect + tie-breaking tournament (score desc, idx asc).
// out: [0..B*K) = indices (as float); [B*K..2BK) = scores.
// ---------------------------------------------------------------------------
__global__ __launch_bounds__(256) void select_topk(
    const float* __restrict__ cs, const int* __restrict__ ci,
    const int* __restrict__ cnt2,
    const int* __restrict__ ocnt, const int* __restrict__ oq,
    const int* __restrict__ og, const float* __restrict__ osv,
    float* __restrict__ out, int CBLK)
{
    __shared__ int   cntRow[CNTL];
    __shared__ int   hist[256];
    __shared__ int   hscan[256];
    __shared__ float Ls[256];
    __shared__ int   Li[256];
    __shared__ int   lcnt, nTotS, bS, gtS;
    __shared__ float wrs[4]; __shared__ int wri[4], wrslot[4];

    const int q = blockIdx.x;
    const int t = threadIdx.x;
    const size_t qbase = (size_t)q * CBLK * SLOTS;
    const size_t cbase = (size_t)q * CBLK;
    const int CC = CBLK < CNTL ? CBLK : CNTL;
    const int novf0 = *ocnt;
    const int novf = novf0 < OCAP ? novf0 : OCAP;
    const int nslots = CBLK * SLOTS;

    for (int i = t; i < CC; i += 256) cntRow[i] = cnt2[cbase + i];
    if (t == 0) nTotS = 0;
    __syncthreads();
    {
        int part = 0;
        for (int i = t; i < CBLK; i += 256)
            part += (i < CNTL) ? cntRow[i] : cnt2[cbase + i];
        for (int i = t; i < novf; i += 256)
            if (oq[i] == q) part++;
        atomicAdd(&nTotS, part);
    }
    __syncthreads();
    const int nTot = nTotS;

    unsigned prefix = 0, pmask = 0;
    int kneed = KTOP;

    if (nTot > KTOP) {
        for (int pass = 0; pass < 4; ++pass) {
            const int shift = 24 - pass * 8;
            hist[t] = 0;
            __syncthreads();
            for (int i = t; i < nslots; i += 256) {
                const int b = i >> 1, sl = i & 1;          // SLOTS = 2
                const int cb = (b < CNTL) ? cntRow[b] : cnt2[cbase + b];
                if (sl < cb) {
                    unsigned k = fkey(cs[qbase + i]);
                    if ((k & pmask) == prefix)
                        atomicAdd(&hist[(k >> shift) & 255], 1);
                }
            }
            for (int i = t; i < novf; i += 256) {
                if (oq[i] == q) {
                    unsigned k = fkey(osv[i]);
                    if ((k & pmask) == prefix)
                        atomicAdd(&hist[(k >> shift) & 255], 1);
                }
            }
            __syncthreads();
            int* src = hist; int* dst = hscan;
            for (int off = 1; off < 256; off <<= 1) {
                int v = src[t] + ((t + off) < 256 ? src[t + off] : 0);
                __syncthreads();
                dst[t] = v;
                __syncthreads();
                int* tmp = src; src = dst; dst = tmp;
            }
            if (src[t] >= kneed && (t == 255 || src[t + 1] < kneed)) {
                bS = t;
                gtS = (t == 255) ? 0 : src[t + 1];
            }
            __syncthreads();
            const int b = bS;
            kneed -= gtS;
            prefix |= ((unsigned)b) << shift;
            pmask  |= 0xFFu << shift;
            __syncthreads();
        }
    }

    if (t == 0) lcnt = 0;
    __syncthreads();
    const unsigned T = (nTot > KTOP) ? prefix : 0u;
    for (int i = t; i < nslots; i += 256) {
        const int b = i >> 1, sl = i & 1;
        const int cb = (b < CNTL) ? cntRow[b] : cnt2[cbase + b];
        if (sl < cb) {
            float s = cs[qbase + i];
            if (fkey(s) >= T) {
                int p = atomicAdd(&lcnt, 1);
                if (p < 256) { Ls[p] = s; Li[p] = ci[qbase + i]; }
            }
        }
    }
    for (int i = t; i < novf; i += 256) {
        if (oq[i] == q) {
            float s = osv[i];
            if (fkey(s) >= T) {
                int p = atomicAdd(&lcnt, 1);
                if (p < 256) { Ls[p] = s; Li[p] = og[i]; }
            }
        }
    }
    __syncthreads();
    const int M = lcnt < 256 ? lcnt : 256;

    const int w = t >> 6, lane = t & 63;
    for (int r = 0; r < KTOP; ++r) {
        float bv = (t < M) ? Ls[t] : NEG_INF;
        int   bi = (t < M) ? Li[t] : 0x7fffffff;
        int   bslot = t;
        #pragma unroll
        for (int off = 32; off > 0; off >>= 1) {
            float ov = __shfl_xor(bv, off);
            int   oi = __shfl_xor(bi, off);
            int   osl = __shfl_xor(bslot, off);
            if (pri_gt(ov, oi, bv, bi)) { bv = ov; bi = oi; bslot = osl; }
        }
        if (lane == 0) { wrs[w] = bv; wri[w] = bi; wrslot[w] = bslot; }
        __syncthreads();
        if (t == 0) {
            float fv = wrs[0]; int fi = wri[0]; int fs = wrslot[0];
            #pragma unroll
            for (int ww = 1; ww < 4; ++ww)
                if (pri_gt(wrs[ww], wri[ww], fv, fi)) {
                    fv = wrs[ww]; fi = wri[ww]; fs = wrslot[ww];
                }
            out[q * KTOP + r]                     = (float)fi;
            out[(size_t)BQ * KTOP + q * KTOP + r] = fv;
            Ls[fs] = NEG_INF; Li[fs] = 0x7fffffff;
        }
        __syncthreads();
    }
}

// ---------------------------------------------------------------------------
extern "C" void kernel_launch(void* const* d_in, const int* in_sizes, int n_in,
                              void* d_out, int out_size, void* d_ws, size_t ws_size,
                              hipStream_t stream)
{
    const float* Qf   = (const float*)d_in[0];
    const float* G    = (const float*)d_in[1];
    const int*   mask = (const int*)d_in[2];
    const int Ntot = in_sizes[1] / DK;                 // 200000

    const int NCH = (Ntot + CHI - 1) / CHI;            // 6250
    const int SC  = GRIDP < NCH ? GRIDP : NCH;         // 768 sampled chunks
    const int grid1 = GRIDP < NCH ? GRIDP : NCH;

    // ws layout (bytes): ~10 MB total
    char* w = (char*)d_ws;
    int*   ocnt = (int*)(w + 0);                       // [0,4096) control
    float* thrm = (float*)(w + 4096);                  // 512 B
    float* gmax = (float*)(w + 8192);                  // SC*128*4
    size_t off = 8192 + (size_t)SC * BQ * 4;
    off = (off + 255) & ~(size_t)255;
    int*   cnt2 = (int*)(w + off);                     // 128*NCH*4
    off += (size_t)BQ * NCH * 4; off = (off + 255) & ~(size_t)255;
    float* cs   = (float*)(w + off);                   // 128*NCH*SLOTS*4
    off += (size_t)BQ * NCH * SLOTS * 4;
    int*   ci   = (int*)(w + off);
    off += (size_t)BQ * NCH * SLOTS * 4;
    int*   oqv  = (int*)(w + off);   off += (size_t)OCAP * 4;
    int*   ogv  = (int*)(w + off);   off += (size_t)OCAP * 4;
    float* osv  = (float*)(w + off);

    (void)hipMemsetAsync(w, 0, 4096, stream);
    score_pass<0><<<dim3(SC), dim3(256), 0, stream>>>(      // sampled maxima
        Qf, G, mask, thrm, gmax, cnt2, cs, ci, ocnt, oqv, ogv, osv,
        Ntot, NCH, SC);
    thr32<<<dim3(BQ), dim3(256), 0, stream>>>(gmax, thrm, SC);
    score_pass<1><<<dim3(grid1), dim3(256), 0, stream>>>(   // full filter
        Qf, G, mask, thrm, gmax, cnt2, cs, ci, ocnt, oqv, ogv, osv,
        Ntot, NCH, SC);
    select_topk<<<dim3(BQ), dim3(256), 0, stream>>>(
        cs, ci, cnt2, ocnt, oqv, ogv, osv, (float*)d_out, NCH);
}